// Round 5
// baseline (130.324 us; speedup 1.0000x reference)
//
#include <hip/hip_runtime.h>
#include <hip/hip_bf16.h>
#include <math.h>

// ---------------------------------------------------------------------------
// SAContrastiveAdversarialLoss on MI355X (gfx950)
// B=8192, D=128, S=64. Output: scalar fp32.
//
// loss = sum_i -log(1e-12 + num_i/denom_i) / (B*(2B-1))
//        + sum_i -log(1e-12 + 1 - picked_i)
//
// v6 structure:
//  - Harness floor: ~43us 256MiB workspace re-poison fill inside the timed
//    region (r3 profile). Our kernels sit on top.
//  - prep: 16 rows/block (1024 thr); normalize rows into padded LDS, emit
//    fragment-tiled A/K2/K1 as contiguous 16B-coalesced stores. Zeroes out.
//  - main: 512 rows x 512 cols per block (8 waves, 2 blocks/CU); phase =
//    32 cols (8KB); 3 LDS buffers; stage issued 2 phases ahead; counted
//    s_waitcnt vmcnt(1) per phase (never 0 in loop); ONE barrier/phase.
//    Depth-2 keeps per-wave live state ~125 regs -> no scratch (v5 lesson:
//    depth-3/vmcnt(4) spilled -> 60MB of scratch writes, +18us).
//  - final_adv: 2048 blocks, one row/wave; one atomicAdd(out) per block.
// ---------------------------------------------------------------------------

#define NROWS 8192
#define DFEAT 128

typedef __bf16 bf16_t;
typedef __bf16 bf16x8 __attribute__((ext_vector_type(8)));
typedef __bf16 bf16x2 __attribute__((ext_vector_type(2)));
typedef float  f32x4  __attribute__((ext_vector_type(4)));

__device__ __forceinline__ float fexp2(float x) {
#if __has_builtin(__builtin_amdgcn_exp2f)
  return __builtin_amdgcn_exp2f(x);
#else
  return exp2f(x);
#endif
}

// async global->LDS, 16B per lane. gsrc is per-lane (includes +lane*16);
// lds dst is wave-uniform base (HW adds lane*16).
__device__ __forceinline__ void stage16(const void* gsrc, void* ldst) {
  __builtin_amdgcn_global_load_lds(
      (const __attribute__((address_space(1))) unsigned int*)gsrc,
      (__attribute__((address_space(3))) unsigned int*)ldst, 16, 0, 0);
}

#define WAITVM(n) asm volatile("s_waitcnt vmcnt(" #n ")" ::: "memory")

// ---------------------------------------------------------------------------
// prep: block = 16 rows = one fragment-tile group. Wave w normalizes row w
// into padded LDS (stride 136 bf16 = 272B). Then threads 0..767 write the
// A / K2 / K1 fragment-tile groups as contiguous coalesced 16B stores:
//   out[tile*2048 + u*8 + j] = L[u&15][(u>>6)*32 + ((u>>4)&3)*8 + j]
// matching the main kernel's fragment layout. Also zeroes out[0].
__global__ __launch_bounds__(1024)
void sa_prep_kernel(const float* __restrict__ z1,
                    const float* __restrict__ z2,
                    bf16_t* __restrict__ Abuf,
                    bf16_t* __restrict__ Kc,
                    float* __restrict__ numv,
                    float* __restrict__ d11v,
                    float* __restrict__ out) {
  __shared__ __align__(16) bf16_t LA[16][136];
  __shared__ __align__(16) bf16_t LK2[16][136];
  __shared__ __align__(16) bf16_t LK1[16][136];

  int wave = threadIdx.x >> 6;   // 0..15 : row within tile
  int lane = threadIdx.x & 63;
  int tile = blockIdx.x;         // 0..511
  int row  = tile * 16 + wave;

  float2 a = ((const float2*)(z1 + (size_t)row * DFEAT))[lane];
  float2 b = ((const float2*)(z2 + (size_t)row * DFEAT))[lane];

  float s1  = a.x * a.x + a.y * a.y;
  float s2  = b.x * b.x + b.y * b.y;
  float s12 = a.x * b.x + a.y * b.y;
#pragma unroll
  for (int m = 32; m; m >>= 1) {
    s1  += __shfl_xor(s1, m, 64);
    s2  += __shfl_xor(s2, m, 64);
    s12 += __shfl_xor(s12, m, 64);
  }
  float r1 = 1.0f / fmaxf(sqrtf(s1), 1e-8f);  // COS_EPS
  float r2 = 1.0f / fmaxf(sqrtf(s2), 1e-8f);

  const float SCL = 14.426950408889634f;  // 10 * log2(e), folds /tau + exp2

  bf16x2 av;  av[0] = (bf16_t)(a.x * r1 * SCL); av[1] = (bf16_t)(a.y * r1 * SCL);
  bf16x2 k2v; k2v[0] = (bf16_t)(b.x * r2);      k2v[1] = (bf16_t)(b.y * r2);
  bf16x2 k1v; k1v[0] = (bf16_t)(a.x * r1);      k1v[1] = (bf16_t)(a.y * r1);

  *(bf16x2*)&LA[wave][2 * lane]  = av;
  *(bf16x2*)&LK2[wave][2 * lane] = k2v;
  *(bf16x2*)&LK1[wave][2 * lane] = k1v;

  if (lane == 0) {
    numv[row] = expf(10.0f * s12 * r1 * r2);
    d11v[row] = expf(10.0f * s1 * r1 * r1);
    if (row == 0) out[0] = 0.0f;
  }
  __syncthreads();

  int t = threadIdx.x;
  if (t < 768) {
    int sel = t >> 8;          // 0=A, 1=K2, 2=K1
    int u   = t & 255;
    int kf  = u >> 6;
    int qk  = (u >> 4) & 3;
    int r16 = u & 15;
    const bf16_t* Ls = (sel == 0) ? &LA[0][0]
                     : (sel == 1) ? &LK2[0][0] : &LK1[0][0];
    bf16x8 v = *(const bf16x8*)(Ls + r16 * 136 + kf * 32 + qk * 8);
    bf16_t* dst = (sel == 0) ? (Abuf + (size_t)tile * 2048)
                : (sel == 1) ? (Kc + (size_t)tile * 2048)
                             : (Kc + (size_t)(512 + tile) * 2048);
    *(bf16x8*)(dst + u * 8) = v;
  }
}

// ---------------------------------------------------------------------------
// main: fused "row-sum of exp(sim)" over the virtual 8192x16384 matrix.
// Block = 512 rows x 512 cols; 8 waves; wave w owns rows [bx*512+w*64, +64).
// Phase = 32 cols (2 tiles, 8KB of Kc), 16 phases, 3 LDS buffers.
// Each wave stages 1KB/phase (one global_load_lds_dwordx4), issued TWO
// phases ahead; per-phase wait = vmcnt(1) (own oldest load = this phase's
// next buffer); ONE s_barrier per phase. Per wave-phase: 32 MFMA + 32 exp2.
// MFMA C/D layout: col=lane&15, row=(lane>>4)*4+reg.
// Partial row-sums (512 cols) -> T2[row][by] plain stores (no atomics).
__global__ __launch_bounds__(512, 4)
void sa_main_kernel(const bf16_t* __restrict__ Abuf,
                    const bf16_t* __restrict__ Kc,
                    float* __restrict__ T2) {
  __shared__ __align__(16) bf16_t bsm[3][4096];  // 3 x 8KB phase buffers

  int wave = threadIdx.x >> 6;   // 0..7
  int lane = threadIdx.x & 63;
  int quad = lane >> 4;

  // bijective XCD swizzle: 512 blocks, 8 XCDs, 64 each. Each XCD sweeps
  // 4 col-chunks (512KB of Kc) + all of A (2MB) -> L2-resident.
  int id     = blockIdx.x;
  int xcd    = id & 7;
  int within = id >> 3;                // 0..63
  int by     = xcd * 4 + (within >> 4);  // 0..31 col-chunk: 512 cols
  int bx     = within & 15;              // 0..15 row-block: 512 rows
  int rowBase = bx * 512 + wave * 64;
  int colBase = by * 512;

  // A fragments for this wave's 4 row-strips (fragment-tiled: consecutive
  // 1KB fragments, fully coalesced 16B/lane).
  const bf16x8* ap = (const bf16x8*)Abuf + (size_t)(rowBase >> 4) * 256 + lane;
  bf16x8 afrag[4][4];
#pragma unroll
  for (int s = 0; s < 4; ++s)
#pragma unroll
    for (int kfi = 0; kfi < 4; ++kfi)
      afrag[s][kfi] = ap[(s * 4 + kfi) * 64];

  f32x4 sums[4];
#pragma unroll
  for (int s = 0; s < 4; ++s) sums[s] = (f32x4){0.f, 0.f, 0.f, 0.f};

  // B stage source: phase p = 8KB at chunk-byte-base + p*8192.
  // Wave w stages 1KB: +w*1024, +lane*16 (linear per-lane, LDS dst uniform).
  const char* bsrc = (const char*)Kc + (size_t)(colBase >> 4) * 4096 +
                     (size_t)wave * 1024 + (size_t)lane * 16;
  char* lw = (char*)&bsm[0][0] + (size_t)wave * 1024;

  auto stagePhase = [&](int p) {
    stage16(bsrc + (size_t)p * 8192, lw + (size_t)(p % 3) * 8192);
  };

  auto computePhase = [&](int p) {
    const bf16_t* base = &bsm[0][0] + (p % 3) * 4096;
#pragma unroll
    for (int tt = 0; tt < 2; ++tt) {
      const bf16x8* bs = (const bf16x8*)(base + tt * 2048);
      bf16x8 bfr[4];
#pragma unroll
      for (int kfi = 0; kfi < 4; ++kfi) bfr[kfi] = bs[kfi * 64 + lane];
#pragma unroll
      for (int s = 0; s < 4; ++s) {
        f32x4 c = {0.f, 0.f, 0.f, 0.f};
        __builtin_amdgcn_s_setprio(1);
#pragma unroll
        for (int kfi = 0; kfi < 4; ++kfi)
          c = __builtin_amdgcn_mfma_f32_16x16x32_bf16(afrag[s][kfi], bfr[kfi],
                                                      c, 0, 0, 0);
        __builtin_amdgcn_s_setprio(0);
#pragma unroll
        for (int r = 0; r < 4; ++r) sums[s][r] += fexp2(c[r]);
      }
    }
  };

  // prologue: 2 phases in flight; drain phase 0, keep phase 1 flying.
  stagePhase(0);
  stagePhase(1);
  WAITVM(1);
  __builtin_amdgcn_s_barrier();
  __builtin_amdgcn_sched_barrier(0);

  // steady state: issue stage(p+2) -> compute(p) -> drain own oldest load
  // (phase p+1's slice) -> barrier. Never drains vmcnt to 0.
#pragma unroll 1
  for (int p = 0; p < 14; ++p) {
    stagePhase(p + 2);
    computePhase(p);
    WAITVM(1);
    __builtin_amdgcn_s_barrier();
    __builtin_amdgcn_sched_barrier(0);
  }
  // epilogue: phases 14, 15 (stage(15) still in flight entering 14).
  computePhase(14);
  WAITVM(0);
  __builtin_amdgcn_s_barrier();
  __builtin_amdgcn_sched_barrier(0);
  computePhase(15);

  // Reduce across the 16 lanes of each quad-group (cols), then one lane
  // per quad commits 4 row partial-sums with plain stores (no atomics).
  int l15 = lane & 15;
#pragma unroll
  for (int s = 0; s < 4; ++s) {
#pragma unroll
    for (int r = 0; r < 4; ++r) {
      float v = sums[s][r];
      v += __shfl_xor(v, 1, 64);
      v += __shfl_xor(v, 2, 64);
      v += __shfl_xor(v, 4, 64);
      v += __shfl_xor(v, 8, 64);
      if (l15 == 0)
        T2[(size_t)(rowBase + s * 16 + quad * 4 + r) * 32 + by] = v;
    }
  }
}

// ---------------------------------------------------------------------------
// final+adv fused: 2048 blocks x 256 threads, one row per wave, fully
// parallel. Reduces the 32 T2 partials per row inside the same 64-lane
// butterfly as the adversarial argmax. One atomicAdd(out) per block.
__global__ __launch_bounds__(256)
void sa_final_adv_kernel(const float* __restrict__ T2,
                         const float* __restrict__ numv,
                         const float* __restrict__ d11v,
                         const float* __restrict__ c,
                         const float* __restrict__ lab,
                         float* __restrict__ out) {
  int wave = threadIdx.x >> 6;
  int lane = threadIdx.x & 63;
  int row  = blockIdx.x * 4 + wave;

  float cv = c[row * 64 + lane];
  float lv = lab[row * 64 + lane];
  float tv = (lane < 32) ? T2[(size_t)row * 32 + lane] : 0.0f;

  float ss = cv * cv;
  float bestv = lv;
  int   besti = lane;
#pragma unroll
  for (int m = 32; m; m >>= 1) {
    ss += __shfl_xor(ss, m, 64);
    tv += __shfl_xor(tv, m, 64);
    float ov = __shfl_xor(bestv, m, 64);
    int   oi = __shfl_xor(besti, m, 64);
    if (ov > bestv || (ov == bestv && oi < besti)) { bestv = ov; besti = oi; }
  }
  float picked = __shfl(cv, besti, 64) / fmaxf(sqrtf(ss), 1e-12f);

  float term = 0.0f;
  if (lane == 0) {
    float denom = tv - d11v[row];  // tv = full row sum of both exp blocks
    term = -logf(1e-12f + numv[row] / denom) * (1.0f / 134209536.0f)
           - logf(1e-12f + 1.0f - picked);  // LAM = 1
  }

  __shared__ float wacc[4];
  if (lane == 0) wacc[wave] = term;
  __syncthreads();
  if (threadIdx.x == 0)
    atomicAdd(out, wacc[0] + wacc[1] + wacc[2] + wacc[3]);
}

// ---------------------------------------------------------------------------
extern "C" void kernel_launch(void* const* d_in, const int* in_sizes, int n_in,
                              void* d_out, int out_size, void* d_ws,
                              size_t ws_size, hipStream_t stream) {
  const float* z1  = (const float*)d_in[0];  // [8192,128]
  const float* z2  = (const float*)d_in[1];  // [8192,128]
  const float* co  = (const float*)d_in[2];  // [8192,64]
  const float* lab = (const float*)d_in[3];  // [8192,64]
  float* out = (float*)d_out;

  char* ws = (char*)d_ws;
  bf16_t* Abuf  = (bf16_t*)ws;                           // 8192*128*2 = 2 MB
  bf16_t* Kc    = (bf16_t*)(ws + 2u * 1024 * 1024);      // 16384*128*2 = 4 MB
  float*  T2    = (float*)(ws + 6u * 1024 * 1024);       // 8192*32*4 = 1 MB
  float*  numv  = (float*)(ws + 7u * 1024 * 1024);       // 32 KB
  float*  d11v  = numv + NROWS;                          // 32 KB

  sa_prep_kernel<<<NROWS / 16, 1024, 0, stream>>>(z1, z2, Abuf, Kc, numv,
                                                  d11v, out);
  sa_main_kernel<<<512, 512, 0, stream>>>(Abuf, Kc, T2);
  sa_final_adv_kernel<<<NROWS / 4, 256, 0, stream>>>(T2, numv, d11v, co, lab,
                                                     out);
}

// Round 6
// 105.994 us; speedup vs baseline: 1.2295x; 1.2295x over previous
//
#include <hip/hip_runtime.h>
#include <hip/hip_bf16.h>
#include <math.h>

// ---------------------------------------------------------------------------
// SAContrastiveAdversarialLoss on MI355X (gfx950)
// B=8192, D=128, S=64. Output: scalar fp32.
//
// loss = sum_i -log(1e-12 + num_i/denom_i) / (B*(2B-1))
//        + sum_i -log(1e-12 + 1 - picked_i)
//
// v7 structure:
//  - Harness floor: ~43us 256MiB workspace re-poison fill inside the timed
//    region (r3 profile). Our kernels sit on top.
//  - prep: 16 rows/block (1024 thr); normalize rows into padded LDS, emit
//    fragment-tiled A/K2/K1 as contiguous 16B-coalesced stores.
//  - main: 512 rows x 256 cols per block; ENTIRE 64KB col-chunk prestaged
//    into LDS (8 x global_load_lds per wave), ONE __syncthreads, then each
//    wave free-runs its 8 phases with ZERO barriers (v6 lesson: per-phase
//    barriers lockstep all waves -> MFMA/VALU alternate at ~29% each; free
//    drift lets the pipes overlap). T2 stores transposed+float4-coalesced
//    (v6's 4B-scatter cost ~17MB write-allocate).
//  - final_adv: 2048 blocks, one row/wave; partial plain store (r5 lesson:
//    2048 block-level same-address atomicAdds cost ~15us); sa_reduce sums.
// ---------------------------------------------------------------------------

#define NROWS 8192
#define DFEAT 128

typedef __bf16 bf16_t;
typedef __bf16 bf16x8 __attribute__((ext_vector_type(8)));
typedef __bf16 bf16x2 __attribute__((ext_vector_type(2)));
typedef float  f32x4  __attribute__((ext_vector_type(4)));

__device__ __forceinline__ float fexp2(float x) {
#if __has_builtin(__builtin_amdgcn_exp2f)
  return __builtin_amdgcn_exp2f(x);
#else
  return exp2f(x);
#endif
}

// async global->LDS, 16B per lane. gsrc is per-lane (includes +lane*16);
// lds dst is wave-uniform base (HW adds lane*16).
__device__ __forceinline__ void stage16(const void* gsrc, void* ldst) {
  __builtin_amdgcn_global_load_lds(
      (const __attribute__((address_space(1))) unsigned int*)gsrc,
      (__attribute__((address_space(3))) unsigned int*)ldst, 16, 0, 0);
}

// ---------------------------------------------------------------------------
// prep: block = 16 rows = one fragment-tile group. Wave w normalizes row w
// into padded LDS (stride 136 bf16 = 272B). Then threads 0..767 write the
// A / K2 / K1 fragment-tile groups as contiguous coalesced 16B stores:
//   out[tile*2048 + u*8 + j] = L[u&15][(u>>6)*32 + ((u>>4)&3)*8 + j]
// matching the main kernel's fragment layout.
__global__ __launch_bounds__(1024)
void sa_prep_kernel(const float* __restrict__ z1,
                    const float* __restrict__ z2,
                    bf16_t* __restrict__ Abuf,
                    bf16_t* __restrict__ Kc,
                    float* __restrict__ numv,
                    float* __restrict__ d11v) {
  __shared__ __align__(16) bf16_t LA[16][136];
  __shared__ __align__(16) bf16_t LK2[16][136];
  __shared__ __align__(16) bf16_t LK1[16][136];

  int wave = threadIdx.x >> 6;   // 0..15 : row within tile
  int lane = threadIdx.x & 63;
  int tile = blockIdx.x;         // 0..511
  int row  = tile * 16 + wave;

  float2 a = ((const float2*)(z1 + (size_t)row * DFEAT))[lane];
  float2 b = ((const float2*)(z2 + (size_t)row * DFEAT))[lane];

  float s1  = a.x * a.x + a.y * a.y;
  float s2  = b.x * b.x + b.y * b.y;
  float s12 = a.x * b.x + a.y * b.y;
#pragma unroll
  for (int m = 32; m; m >>= 1) {
    s1  += __shfl_xor(s1, m, 64);
    s2  += __shfl_xor(s2, m, 64);
    s12 += __shfl_xor(s12, m, 64);
  }
  float r1 = 1.0f / fmaxf(sqrtf(s1), 1e-8f);  // COS_EPS
  float r2 = 1.0f / fmaxf(sqrtf(s2), 1e-8f);

  const float SCL = 14.426950408889634f;  // 10 * log2(e), folds /tau + exp2

  bf16x2 av;  av[0] = (bf16_t)(a.x * r1 * SCL); av[1] = (bf16_t)(a.y * r1 * SCL);
  bf16x2 k2v; k2v[0] = (bf16_t)(b.x * r2);      k2v[1] = (bf16_t)(b.y * r2);
  bf16x2 k1v; k1v[0] = (bf16_t)(a.x * r1);      k1v[1] = (bf16_t)(a.y * r1);

  *(bf16x2*)&LA[wave][2 * lane]  = av;
  *(bf16x2*)&LK2[wave][2 * lane] = k2v;
  *(bf16x2*)&LK1[wave][2 * lane] = k1v;

  if (lane == 0) {
    numv[row] = expf(10.0f * s12 * r1 * r2);
    d11v[row] = expf(10.0f * s1 * r1 * r1);
  }
  __syncthreads();

  int t = threadIdx.x;
  if (t < 768) {
    int sel = t >> 8;          // 0=A, 1=K2, 2=K1
    int u   = t & 255;
    int kf  = u >> 6;
    int qk  = (u >> 4) & 3;
    int r16 = u & 15;
    const bf16_t* Ls = (sel == 0) ? &LA[0][0]
                     : (sel == 1) ? &LK2[0][0] : &LK1[0][0];
    bf16x8 v = *(const bf16x8*)(Ls + r16 * 136 + kf * 32 + qk * 8);
    bf16_t* dst = (sel == 0) ? (Abuf + (size_t)tile * 2048)
                : (sel == 1) ? (Kc + (size_t)tile * 2048)
                             : (Kc + (size_t)(512 + tile) * 2048);
    *(bf16x8*)(dst + u * 8) = v;
  }
}

// ---------------------------------------------------------------------------
// main: fused "row-sum of exp(sim)" over the virtual 8192x16384 matrix.
// Block = 512 rows x 256 cols; 8 waves; wave w owns rows [bx*512+w*64, +64).
// Prologue: the whole 64KB chunk of Kc is staged into LDS (each wave stages
// its 8KB slice = 8 x global_load_lds_dwordx4), ONE __syncthreads.
// Then NO further synchronization: each wave computes 8 phases (32 cols
// each) in rotated order, pure LDS reads. Waves drift -> MFMA/VALU overlap.
// MFMA C/D layout: col=lane&15, row=(lane>>4)*4+reg.
// Partial row-sums -> T2t[by][row], one float4 per writer lane (coalesced).
__global__ __launch_bounds__(512, 4)
void sa_main_kernel(const bf16_t* __restrict__ Abuf,
                    const bf16_t* __restrict__ Kc,
                    float* __restrict__ T2t) {
  __shared__ __align__(16) bf16_t bsm[32768];  // 64KB: 256 cols x 128 k

  int wave = threadIdx.x >> 6;   // 0..7
  int lane = threadIdx.x & 63;
  int quad = lane >> 4;

  // bijective XCD swizzle: 1024 blocks, 8 XCDs, 128 each. Each XCD sweeps
  // 8 col-chunks (512KB of Kc) + all of A (2MB) -> L2-resident.
  int id     = blockIdx.x;
  int xcd    = id & 7;
  int within = id >> 3;                 // 0..127
  int by     = xcd * 8 + (within >> 4); // 0..63 col-chunk: 256 cols
  int bx     = within & 15;             // 0..15 row-block: 512 rows
  int rowBase = bx * 512 + wave * 64;

  // A fragments for this wave's 4 row-strips (fragment-tiled: consecutive
  // 1KB fragments, fully coalesced 16B/lane).
  const bf16x8* ap = (const bf16x8*)Abuf + (size_t)(rowBase >> 4) * 256 + lane;
  bf16x8 afrag[4][4];
#pragma unroll
  for (int s = 0; s < 4; ++s)
#pragma unroll
    for (int kfi = 0; kfi < 4; ++kfi)
      afrag[s][kfi] = ap[(s * 4 + kfi) * 64];

  // Stage the whole 64KB chunk: wave w covers bytes [w*8KB, (w+1)*8KB).
  // Chunk by = 16 fragment-tiles = 64KB contiguous at Kc + by*65536B.
  const char* src = (const char*)Kc + (size_t)by * 65536 +
                    (size_t)wave * 8192 + (size_t)lane * 16;
  char* dst = (char*)&bsm[0] + wave * 8192;  // wave-uniform LDS dst
#pragma unroll
  for (int i = 0; i < 8; ++i) stage16(src + i * 1024, dst + i * 1024);

  __syncthreads();  // only barrier in the kernel; LDS read-only afterwards

  f32x4 sums[4];
#pragma unroll
  for (int s = 0; s < 4; ++s) sums[s] = (f32x4){0.f, 0.f, 0.f, 0.f};

  // 8 phases x 32 cols, rotated start per wave; no sync, waves free-run.
#pragma unroll 1
  for (int i = 0; i < 8; ++i) {
    int p = (wave + i) & 7;
    const bf16_t* base = &bsm[0] + p * 4096;
#pragma unroll
    for (int tt = 0; tt < 2; ++tt) {
      const bf16x8* bs = (const bf16x8*)(base + tt * 2048);
      bf16x8 bfr[4];
#pragma unroll
      for (int kfi = 0; kfi < 4; ++kfi) bfr[kfi] = bs[kfi * 64 + lane];
#pragma unroll
      for (int s = 0; s < 4; ++s) {
        f32x4 c = {0.f, 0.f, 0.f, 0.f};
        __builtin_amdgcn_s_setprio(1);
#pragma unroll
        for (int kfi = 0; kfi < 4; ++kfi)
          c = __builtin_amdgcn_mfma_f32_16x16x32_bf16(afrag[s][kfi], bfr[kfi],
                                                      c, 0, 0, 0);
        __builtin_amdgcn_s_setprio(0);
#pragma unroll
        for (int r = 0; r < 4; ++r) sums[s][r] += fexp2(c[r]);
      }
    }
  }

  // Reduce across the 16 lanes of each quad-group (cols); writer lane packs
  // its 4 row-sums into ONE float4 store (quads 0..3 -> contiguous 64B).
  int l15 = lane & 15;
#pragma unroll
  for (int s = 0; s < 4; ++s) {
    f32x4 st;
#pragma unroll
    for (int r = 0; r < 4; ++r) {
      float v = sums[s][r];
      v += __shfl_xor(v, 1, 64);
      v += __shfl_xor(v, 2, 64);
      v += __shfl_xor(v, 4, 64);
      v += __shfl_xor(v, 8, 64);
      st[r] = v;
    }
    if (l15 == 0)
      *(f32x4*)(T2t + (size_t)by * 8192 + rowBase + s * 16 + quad * 4) = st;
  }
}

// ---------------------------------------------------------------------------
// final+adv fused: 2048 blocks x 256 threads, one row per wave, fully
// parallel. Lane l contributes T2t[l][row] (L2-resident 2MB); summed in the
// same 64-lane butterfly as the adversarial argmax. Partial -> plain store.
__global__ __launch_bounds__(256)
void sa_final_adv_kernel(const float* __restrict__ T2t,
                         const float* __restrict__ numv,
                         const float* __restrict__ d11v,
                         const float* __restrict__ c,
                         const float* __restrict__ lab,
                         float* __restrict__ partial) {
  int wave = threadIdx.x >> 6;
  int lane = threadIdx.x & 63;
  int row  = blockIdx.x * 4 + wave;

  float cv = c[row * 64 + lane];
  float lv = lab[row * 64 + lane];
  float tv = T2t[(size_t)lane * 8192 + row];  // 64 chunk-partials per row

  float ss = cv * cv;
  float bestv = lv;
  int   besti = lane;
#pragma unroll
  for (int m = 32; m; m >>= 1) {
    ss += __shfl_xor(ss, m, 64);
    tv += __shfl_xor(tv, m, 64);
    float ov = __shfl_xor(bestv, m, 64);
    int   oi = __shfl_xor(besti, m, 64);
    if (ov > bestv || (ov == bestv && oi < besti)) { bestv = ov; besti = oi; }
  }
  float picked = __shfl(cv, besti, 64) / fmaxf(sqrtf(ss), 1e-12f);

  float term = 0.0f;
  if (lane == 0) {
    float denom = tv - d11v[row];  // tv = full row sum of both exp blocks
    term = -logf(1e-12f + numv[row] / denom) * (1.0f / 134209536.0f)
           - logf(1e-12f + 1.0f - picked);  // LAM = 1
  }

  __shared__ float wacc[4];
  if (lane == 0) wacc[wave] = term;
  __syncthreads();
  if (threadIdx.x == 0)
    partial[blockIdx.x] = wacc[0] + wacc[1] + wacc[2] + wacc[3];
}

// ---------------------------------------------------------------------------
// reduce: single block sums the 2048 block partials -> out (plain store).
__global__ __launch_bounds__(256)
void sa_reduce_kernel(const float* __restrict__ partial,
                      float* __restrict__ out) {
  float v = 0.0f;
#pragma unroll
  for (int i = 0; i < 8; ++i) v += partial[threadIdx.x + 256 * i];
#pragma unroll
  for (int m = 32; m; m >>= 1) v += __shfl_xor(v, m, 64);
  __shared__ float wacc[4];
  if ((threadIdx.x & 63) == 0) wacc[threadIdx.x >> 6] = v;
  __syncthreads();
  if (threadIdx.x == 0) out[0] = wacc[0] + wacc[1] + wacc[2] + wacc[3];
}

// ---------------------------------------------------------------------------
extern "C" void kernel_launch(void* const* d_in, const int* in_sizes, int n_in,
                              void* d_out, int out_size, void* d_ws,
                              size_t ws_size, hipStream_t stream) {
  const float* z1  = (const float*)d_in[0];  // [8192,128]
  const float* z2  = (const float*)d_in[1];  // [8192,128]
  const float* co  = (const float*)d_in[2];  // [8192,64]
  const float* lab = (const float*)d_in[3];  // [8192,64]
  float* out = (float*)d_out;

  char* ws = (char*)d_ws;
  bf16_t* Abuf  = (bf16_t*)ws;                           // 8192*128*2 = 2 MB
  bf16_t* Kc    = (bf16_t*)(ws + 2u * 1024 * 1024);      // 16384*128*2 = 4 MB
  float*  T2t   = (float*)(ws + 6u * 1024 * 1024);       // 64*8192*4 = 2 MB
  float*  numv  = (float*)(ws + 8u * 1024 * 1024);       // 32 KB
  float*  d11v  = numv + NROWS;                          // 32 KB
  float*  part  = d11v + NROWS;                          // 8 KB

  sa_prep_kernel<<<NROWS / 16, 1024, 0, stream>>>(z1, z2, Abuf, Kc, numv,
                                                  d11v);
  sa_main_kernel<<<1024, 512, 0, stream>>>(Abuf, Kc, T2t);
  sa_final_adv_kernel<<<NROWS / 4, 256, 0, stream>>>(T2t, numv, d11v, co, lab,
                                                     part);
  sa_reduce_kernel<<<1, 256, 0, stream>>>(part, out);
}